// Round 6
// baseline (626.237 us; speedup 1.0000x reference)
//
#include <hip/hip_runtime.h>
#include <stdint.h>

// ---------------------------------------------------------------------------
// OwnMultiHeadTransformer: B=4, S=2048, D=1024, H=16, HD=64, FF=4096
// fp32 I/O, bf16 MFMA internal.
//   0) cvt_all: fp32 inputs -> bf16 in d_ws
//   1) gemm128<2>: QKV projection; Q scaled by log2e/32; V stored transposed
//   2) flash_attn: no-max exp2 softmax, S^T orientation (R3/R8)
//   3) gemm128<1>: FFN1 + relu
//   4) gemm128<0>: FFN2 -> d_out (fp32)
// R8: flash_attn issue-early K/V staging + counted vmcnt + ones-MFMA rowsum
//     (97 -> 80.4 us measured; Mfma 30->41%).
// R9-R11: 256x256 deep-pipe GEMM attempts ALL regressed (109-152 us vs ~65
//     for gemm128 QKV; MfmaUtil 13-18%). Falsified for this problem:
//     1 block/CU kills inter-block TLP (m114 overlap), QKV grid=384 at
//     1 blk/CU = 1.5 dispatch rounds (25% idle), K=1024 = 16 K-tiles never
//     amortizes the deep pipeline. REVERTED to all-gemm128.
// R12: gemm128 __launch_bounds__ (256,4) -> (256,5). 5 x 32768 B = exactly
//     160 KiB LDS -> 5 blocks/CU possible; VGPR ~100 << 409 cap. 25% more
//     TLP to cover the per-K-tile barrier drain (the m97 ~20% stall).
//     Zero-downside: if the 5th block doesn't fit, HW runs 4 = R1 parity.
// R13: resubmit of R12 verbatim — R5's bench failed on container acquisition
//     (infra, "MI355X container failed twice"), no counters were produced.
// ---------------------------------------------------------------------------

typedef __attribute__((ext_vector_type(8))) short bf16x8;
typedef __attribute__((ext_vector_type(4))) float f32x4;

__device__ __forceinline__ float bf2f(unsigned short u) {
  union { float f; uint32_t i; } v; v.i = ((uint32_t)u) << 16; return v.f;
}
__device__ __forceinline__ unsigned short f2bf(float f) {
  union { float f; uint32_t i; } v; v.f = f;
  uint32_t i = v.i;
  return (unsigned short)((i + 0x7fffu + ((i >> 16) & 1u)) >> 16);  // RNE
}

#if __has_builtin(__builtin_amdgcn_exp2f)
#define EXP2(x) __builtin_amdgcn_exp2f(x)
#else
#define EXP2(x) __expf((x) * 0.6931471805599453f)
#endif

// pack two f32 -> two bf16 (RNE) in one instr; lo gets p0
__device__ __forceinline__ uint32_t cvtpk(float p0, float p1) {
  uint32_t r;
  asm("v_cvt_pk_bf16_f32 %0, %1, %2" : "=v"(r) : "v"(p0), "v"(p1));
  return r;
}

// async 16B global->LDS (wave-uniform base + lane*16 via tid-linear chunks)
__device__ __forceinline__ void gld16(const void* g, void* l) {
  __builtin_amdgcn_global_load_lds(
      (const __attribute__((address_space(1))) uint32_t*)(uintptr_t)g,
      (__attribute__((address_space(3))) uint32_t*)(uintptr_t)l, 16, 0, 0);
}

#define SCALE_Q 0.04508422002778011f  /* log2(e) / sqrt(D=1024) */

// ---- ws layout (bf16 element offsets) -------------------------------------
#define W1B          0
#define W2B    4194304
#define B1B    8388608
#define B2B    8392704
#define BQB    8393728
#define BKB    8394752
#define BVB    8395776
#define EMBB   8396800
#define WQB   16785408
#define WKB   17833984
#define WVB   18882560
#define QOFF  19931136
#define KOFF  28319744
#define VTOFF 36708352
#define HCOFF 45096960        /* peak 53485568 elems = 102 MiB */
#define HIDOFF 8396800        /* hid overlays dead emb/Wqkv regions */

// ---- 0) fp32 -> bf16 ------------------------------------------------------
__global__ void cvt_all(const float* __restrict__ emb, const float* __restrict__ Wq,
                        const float* __restrict__ bq,  const float* __restrict__ Wk,
                        const float* __restrict__ bk,  const float* __restrict__ Wv,
                        const float* __restrict__ bv,  const float* __restrict__ W1,
                        const float* __restrict__ b1,  const float* __restrict__ W2,
                        const float* __restrict__ b2,  unsigned short* __restrict__ ws) {
  const int i4 = blockIdx.x * 256 + threadIdx.x;
  if (i4 >= 4982784) return;
  const float* s; unsigned short* d; int base;
  if      (i4 < 2097152) { s = emb; d = ws + EMBB; base = 0; }
  else if (i4 < 2359296) { s = Wq;  d = ws + WQB;  base = 2097152; }
  else if (i4 < 2621440) { s = Wk;  d = ws + WKB;  base = 2359296; }
  else if (i4 < 2883584) { s = Wv;  d = ws + WVB;  base = 2621440; }
  else if (i4 < 3932160) { s = W1;  d = ws + W1B;  base = 2883584; }
  else if (i4 < 4980736) { s = W2;  d = ws + W2B;  base = 3932160; }
  else if (i4 < 4980992) { s = bq;  d = ws + BQB;  base = 4980736; }
  else if (i4 < 4981248) { s = bk;  d = ws + BKB;  base = 4980992; }
  else if (i4 < 4981504) { s = bv;  d = ws + BVB;  base = 4981248; }
  else if (i4 < 4982528) { s = b1;  d = ws + B1B;  base = 4981504; }
  else                   { s = b2;  d = ws + B2B;  base = 4982528; }
  const int j = i4 - base;
  const float4 v = ((const float4*)s)[j];
  ushort4 o;
  o.x = f2bf(v.x); o.y = f2bf(v.y); o.z = f2bf(v.z); o.w = f2bf(v.w);
  *(ushort4*)(d + (size_t)j * 4) = o;
}

// ---- GEMM: MODE 0 = bias (fp32 out), 1 = bias+relu, 2 = QKV routing -------
// 128x128 tile, BK=64. Requires K % 64 == 0 and 64 total row-tiles.
template <int MODE>
__launch_bounds__(256, 5)
__global__ void gemm128(const unsigned short* __restrict__ A,
                        const unsigned short* __restrict__ W0,
                        const unsigned short* __restrict__ W1p,
                        const unsigned short* __restrict__ W2p,
                        const unsigned short* __restrict__ bias0,
                        const unsigned short* __restrict__ bias1,
                        const unsigned short* __restrict__ bias2,
                        unsigned short* __restrict__ out0,
                        unsigned short* __restrict__ out1,
                        unsigned short* __restrict__ out2,
                        float* __restrict__ foutp,
                        int N, int K) {
  __shared__ unsigned short At[128 * 64];
  __shared__ unsigned short Bt[128 * 64];
  const int tid  = threadIdx.x;
  const int wave = tid >> 6, lane = tid & 63;
  const int quad = lane >> 4, l15 = lane & 15;

  // XCD swizzle: xcd = lid&7 owns rows ≡ xcd (mod 8), col-panels of 8.
  const int lid = blockIdx.x + blockIdx.y * gridDim.x;
  const int s_ = lid >> 3;
  const int rowBase = (((lid & 7) + ((s_ & 7) << 3)) << 7);
  const int colBase = ((s_ >> 3) << 7);

  const unsigned short* W = W0;
  const unsigned short* bias = bias0;
  int colW = colBase;
  if (MODE == 2) {
    const int which = colBase >> 10;
    if (which == 1) { W = W1p; bias = bias1; }
    if (which == 2) { W = W2p; bias = bias2; }
    colW = colBase & 1023;
  }

  // Staging: 1024 16B chunks/tile; phys chunk u = row*8 + cc holds logical
  // k-chunk ec = cc ^ (row&7). 8 consecutive lanes = one row's full 128B.
  const unsigned short* gA[4]; const unsigned short* gB[4];
  unsigned short *lA[4], *lB[4];
#pragma unroll
  for (int i = 0; i < 4; ++i) {
    const int u = tid + 256 * i;
    const int r = u >> 3, e = (((u & 7) ^ (r & 7)) * 8);
    gA[i] = A + (size_t)(rowBase + r) * K + e;
    gB[i] = W + (size_t)(colW + r) * K + e;
    lA[i] = At + u * 8;
    lB[i] = Bt + u * 8;
  }

  // Fragment offsets: row ra, logical k-chunk q8 = quad + 4*kk ->
  // addr = ra*64 + ((q8 ^ (ra&7))*8). 128B rows -> worst 2-way (free).
  const int wrow = (wave & 1) * 64, wcol = (wave >> 1) * 64;
  int aoff[2][4], boff[2][4];
#pragma unroll
  for (int kk = 0; kk < 2; ++kk)
#pragma unroll
    for (int t = 0; t < 4; ++t) {
      const int ra = wrow + t * 16 + l15;
      aoff[kk][t] = ra * 64 + (((quad + 4 * kk) ^ (ra & 7)) * 8);
      const int rb = wcol + t * 16 + l15;
      boff[kk][t] = rb * 64 + (((quad + 4 * kk) ^ (rb & 7)) * 8);
    }

  f32x4 acc[4][4] = {};
  for (int k0 = 0; k0 < K; k0 += 64) {
    __syncthreads();
#pragma unroll
    for (int i = 0; i < 4; ++i) { gld16(gA[i], lA[i]); gld16(gB[i], lB[i]); }
#pragma unroll
    for (int i = 0; i < 4; ++i) { gA[i] += 64; gB[i] += 64; }
    __syncthreads();
#pragma unroll
    for (int kk = 0; kk < 2; ++kk) {
      bf16x8 af[4], bfr[4];
#pragma unroll
      for (int t = 0; t < 4; ++t) af[t]  = *(const bf16x8*)(At + aoff[kk][t]);
#pragma unroll
      for (int t = 0; t < 4; ++t) bfr[t] = *(const bf16x8*)(Bt + boff[kk][t]);
#pragma unroll
      for (int mt = 0; mt < 4; ++mt)
#pragma unroll
        for (int nt = 0; nt < 4; ++nt)
          acc[mt][nt] = __builtin_amdgcn_mfma_f32_16x16x32_bf16(
              af[mt], bfr[nt], acc[mt][nt], 0, 0, 0);
    }
  }

#pragma unroll
  for (int mt = 0; mt < 4; ++mt) {
    const int row = rowBase + wrow + mt * 16 + quad * 4;
#pragma unroll
    for (int nt = 0; nt < 4; ++nt) {
      const int cIn = colW + wcol + nt * 16 + l15;
      const float bv = bf2f(bias[cIn]);
      if (MODE == 2) {
        const int which = colBase >> 10;
        const int h = cIn >> 6, e = cIn & 63;
#pragma unroll
        for (int r = 0; r < 4; ++r) {
          const int tok = row + r;
          const int b = tok >> 11, s = tok & 2047;
          const float v = acc[mt][nt][r] + bv;
          const size_t bh = (size_t)(b * 16 + h);
          if (which == 0)      out0[(bh * 2048 + s) * 64 + e] = f2bf(v * SCALE_Q);
          else if (which == 1) out1[(bh * 2048 + s) * 64 + e] = f2bf(v);
          else                 out2[(bh * 64 + e) * 2048 + s] = f2bf(v);  // V^T
        }
      } else if (MODE == 1) {
#pragma unroll
        for (int r = 0; r < 4; ++r) {
          const float v = fmaxf(acc[mt][nt][r] + bv, 0.0f);
          out0[(size_t)(row + r) * N + cIn] = f2bf(v);
        }
      } else {
#pragma unroll
        for (int r = 0; r < 4; ++r)
          foutp[(size_t)(row + r) * N + cIn] = acc[mt][nt][r] + bv;
      }
    }
  }
}

// ---- flash attention (R3/R8): S^T orientation, no-max exp2 softmax --------
// grid (16, 64): logical (q-block, b*16+h); XCD-swizzled.
// R8 schedule per iter (raw barriers, counted vmcnt):
//   a: issue K(it+1) -> Kt[buf^1]
//   b: QK^T from Kt[buf] + softmax + P pack (per-wave LDS)
//   c: s_waitcnt vmcnt(2) [own V(it) landed; K(it+1) stays in flight]
//      s_barrier            [all waves' V(it) landed; Kt[buf] reads done]
//   d: PV + ones-MFMA row-sum l
//   e: s_waitcnt vmcnt(0) [own K(it+1) landed]
//      s_barrier            [all waves done reading Vs + all K(it+1) landed]
//   f: issue V(it+1) -> Vs  (skipped at it=31 so kernel ends with vmcnt=0)
__launch_bounds__(256, 4)
__global__ void flash_attn(const unsigned short* __restrict__ Q,
                           const unsigned short* __restrict__ Kg,
                           const unsigned short* __restrict__ Vt,
                           unsigned short* __restrict__ Hc) {
  __shared__ unsigned short Kt[2 * 64 * 64];  // K tile dbuf [t][e], chunk-swizzled
  __shared__ unsigned short Vs[64 * 64];      // V^T tile [e][t], chunk-swizzled
  __shared__ unsigned short Pl[4][32 * 64];   // per-wave P [q][t], chunk-swizzled
  const int tid  = threadIdx.x;
  const int wave = tid >> 6, lane = tid & 63;
  const int quad = lane >> 4, l15 = lane & 15;

  // XCD swizzle: 8 bh's per XCD, q-blocks iterated within -> KV hot in L2.
  const int lid = blockIdx.x + blockIdx.y * gridDim.x;
  const int s_ = lid >> 3;
  const int bh = (lid & 7) + ((s_ & 7) << 3);
  const int q0 = ((s_ >> 3) << 7) + wave * 32;

  const size_t base = (size_t)bh * (2048 * 64);
  const unsigned short* Qb = Q  + base;
  const unsigned short* Kb = Kg + base;
  const unsigned short* Vb = Vt + base;   // [64 e][2048 t]

  // Q fragments (MFMA B operand for S^T: n=q=l15, k=e=quad*8+j)
  bf16x8 qf[2][2];
#pragma unroll
  for (int qt = 0; qt < 2; ++qt) {
    const int q = q0 + qt * 16 + l15;
#pragma unroll
    for (int kk = 0; kk < 2; ++kk)
      qf[qt][kk] = *(const bf16x8*)(Qb + (size_t)q * 64 + kk * 32 + quad * 8);
  }

  // KV staging (8-elem chunk swizzle: ec = cc ^ (row&7); 8 lanes = one 128B row)
  const int u0 = tid, u1 = tid + 256;
  const int kr0 = u0 >> 3, kc0 = (((u0 & 7) ^ (kr0 & 7)) * 8);
  const int kr1 = u1 >> 3, kc1 = (((u1 & 7) ^ (kr1 & 7)) * 8);
  const unsigned short* gK0 = Kb + (size_t)kr0 * 64 + kc0;
  const unsigned short* gK1 = Kb + (size_t)kr1 * 64 + kc1;
  const unsigned short* gV0 = Vb + (size_t)kr0 * 2048 + kc0;
  const unsigned short* gV1 = Vb + (size_t)kr1 * 2048 + kc1;
  unsigned short* lK0 = Kt + u0 * 8;
  unsigned short* lK1 = Kt + u1 * 8;
  unsigned short* lV0 = Vs + u0 * 8;
  unsigned short* lV1 = Vs + u1 * 8;

  // prologue: tile 0 into Kt[0] / Vs, full drain
  gld16(gK0, lK0); gld16(gK1, lK1);
  gld16(gV0, lV0); gld16(gV1, lV1);
  gK0 += 4096; gK1 += 4096; gV0 += 64; gV1 += 64;
  __syncthreads();

  const short oneb = (short)0x3F80;  // bf16 1.0
  const bf16x8 ones = {oneb, oneb, oneb, oneb, oneb, oneb, oneb, oneb};
  f32x4 o[2][4] = {};
  f32x4 lacc[2] = {};
  unsigned short* Pw = Pl[wave];

  for (int it = 0; it < 32; ++it) {
    const int nb = ((it + 1) & 1) * 4096;
    // (a) prefetch next K tile into the other buffer
    gld16(gK0, lK0 + nb); gld16(gK1, lK1 + nb);
    gK0 += 4096; gK1 += 4096;

    const unsigned short* Kc = Kt + (it & 1) * 4096;

    // (b) S^T = K Q^T : C row = t_local = tt*16+quad*4+r, col = q = qt*16+l15
    f32x4 st[4][2] = {};
    __builtin_amdgcn_s_setprio(1);
#pragma unroll
    for (int tt = 0; tt < 4; ++tt) {
      const int t = tt * 16 + l15;
      const bf16x8 kf0 = *(const bf16x8*)(Kc + t * 64 + ((quad       ^ (t & 7)) * 8));
      const bf16x8 kf1 = *(const bf16x8*)(Kc + t * 64 + (((quad + 4) ^ (t & 7)) * 8));
#pragma unroll
      for (int qt = 0; qt < 2; ++qt) {
        st[tt][qt] = __builtin_amdgcn_mfma_f32_16x16x32_bf16(kf0, qf[qt][0], st[tt][qt], 0, 0, 0);
        st[tt][qt] = __builtin_amdgcn_mfma_f32_16x16x32_bf16(kf1, qf[qt][1], st[tt][qt], 0, 0, 0);
      }
    }
    __builtin_amdgcn_s_setprio(0);

    // p = exp2(s) (no max: scores bounded), pack -> P[q][t] LDS (per-wave)
#pragma unroll
    for (int tt = 0; tt < 4; ++tt) {
      const int tc = tt * 2 + (quad >> 1);
#pragma unroll
      for (int qt = 0; qt < 2; ++qt) {
        const float p0 = EXP2(st[tt][qt][0]);
        const float p1 = EXP2(st[tt][qt][1]);
        const float p2 = EXP2(st[tt][qt][2]);
        const float p3 = EXP2(st[tt][qt][3]);
        uint2 w;
        w.x = cvtpk(p0, p1);
        w.y = cvtpk(p2, p3);
        const int qrow = qt * 16 + l15;
        *(uint2*)(Pw + qrow * 64 + ((tc ^ (qrow & 7)) * 8) + (quad & 1) * 4) = w;
      }
    }

    // (c) own V(it) landed (K(it+1) stays in flight), then all-waves barrier
    asm volatile("s_waitcnt vmcnt(2)" ::: "memory");
    __builtin_amdgcn_s_barrier();

    // (d) O += P V ; l += P * 1  (same-wave LDS round-trip, lgkm-ordered)
    bf16x8 pf[2][2];
#pragma unroll
    for (int mt = 0; mt < 2; ++mt) {
      const int qq = mt * 16 + l15;
      pf[mt][0] = *(const bf16x8*)(Pw + qq * 64 + ((quad       ^ (qq & 7)) * 8));
      pf[mt][1] = *(const bf16x8*)(Pw + qq * 64 + (((quad + 4) ^ (qq & 7)) * 8));
    }
    __builtin_amdgcn_s_setprio(1);
#pragma unroll
    for (int nt = 0; nt < 4; ++nt) {
      const int e = nt * 16 + l15;
      const bf16x8 vf0 = *(const bf16x8*)(Vs + e * 64 + ((quad       ^ (e & 7)) * 8));
      const bf16x8 vf1 = *(const bf16x8*)(Vs + e * 64 + (((quad + 4) ^ (e & 7)) * 8));
#pragma unroll
      for (int mt = 0; mt < 2; ++mt) {
        o[mt][nt] = __builtin_amdgcn_mfma_f32_16x16x32_bf16(pf[mt][0], vf0, o[mt][nt], 0, 0, 0);
        o[mt][nt] = __builtin_amdgcn_mfma_f32_16x16x32_bf16(pf[mt][1], vf1, o[mt][nt], 0, 0, 0);
      }
    }
    // row-sum l: D[q][*] = sum_t P[q][t]; rows match o's C-layout rows.
#pragma unroll
    for (int mt = 0; mt < 2; ++mt) {
      lacc[mt] = __builtin_amdgcn_mfma_f32_16x16x32_bf16(pf[mt][0], ones, lacc[mt], 0, 0, 0);
      lacc[mt] = __builtin_amdgcn_mfma_f32_16x16x32_bf16(pf[mt][1], ones, lacc[mt], 0, 0, 0);
    }
    __builtin_amdgcn_s_setprio(0);

    // (e) own K(it+1) landed + all waves done reading Vs
    asm volatile("s_waitcnt vmcnt(0)" ::: "memory");
    __builtin_amdgcn_s_barrier();

    // (f) prefetch next V tile (skip last so kernel ends with vmcnt=0)
    if (it < 31) {
      gld16(gV0, lV0); gld16(gV1, lV1);
      gV0 += 64; gV1 += 64;
    }
  }

  const int b = bh >> 4, h = bh & 15;
#pragma unroll
  for (int mt = 0; mt < 2; ++mt)
#pragma unroll
    for (int r = 0; r < 4; ++r) {
      const int qg = q0 + mt * 16 + quad * 4 + r;
      const float inv = __builtin_amdgcn_rcpf(lacc[mt][r]);
#pragma unroll
      for (int nt = 0; nt < 4; ++nt) {
        const int e = nt * 16 + l15;
        Hc[((size_t)b * 2048 + qg) * 1024 + h * 64 + e] = f2bf(o[mt][nt][r] * inv);
      }
    }
}

extern "C" void kernel_launch(void* const* d_in, const int* in_sizes, int n_in,
                              void* d_out, int out_size, void* d_ws, size_t ws_size,
                              hipStream_t stream) {
  const float* emb = (const float*)d_in[0];
  const float* Wq  = (const float*)d_in[1];
  const float* bq  = (const float*)d_in[2];
  const float* Wk  = (const float*)d_in[3];
  const float* bk  = (const float*)d_in[4];
  const float* Wv  = (const float*)d_in[5];
  const float* bv  = (const float*)d_in[6];
  const float* W1  = (const float*)d_in[7];
  const float* b1  = (const float*)d_in[8];
  const float* W2  = (const float*)d_in[9];
  const float* b2  = (const float*)d_in[10];

  unsigned short* ws = (unsigned short*)d_ws;
  float* out = (float*)d_out;

  cvt_all<<<19465, 256, 0, stream>>>(emb, Wq, bq, Wk, bk, Wv, bv, W1, b1, W2, b2, ws);
  gemm128<2><<<dim3(24, 64), 256, 0, stream>>>(
      ws + EMBB, ws + WQB, ws + WKB, ws + WVB, ws + BQB, ws + BKB, ws + BVB,
      ws + QOFF, ws + KOFF, ws + VTOFF, nullptr, 3072, 1024);
  flash_attn<<<dim3(16, 64), 256, 0, stream>>>(ws + QOFF, ws + KOFF, ws + VTOFF, ws + HCOFF);
  gemm128<1><<<dim3(32, 64), 256, 0, stream>>>(
      ws + HCOFF, ws + W1B, nullptr, nullptr, ws + B1B, nullptr, nullptr,
      ws + HIDOFF, nullptr, nullptr, nullptr, 4096, 1024);
  gemm128<0><<<dim3(8, 64), 256, 0, stream>>>(
      ws + HIDOFF, ws + W2B, nullptr, nullptr, ws + B2B, nullptr, nullptr,
      nullptr, nullptr, nullptr, out, 1024, 4096);
}

// Round 7
// 401.883 us; speedup vs baseline: 1.5583x; 1.5583x over previous
//
#include <hip/hip_runtime.h>
#include <stdint.h>

// ---------------------------------------------------------------------------
// OwnMultiHeadTransformer: B=4, S=2048, D=1024, H=16, HD=64, FF=4096
// fp32 I/O, bf16 MFMA internal.
//   0) cvt_all: fp32 inputs -> bf16 in d_ws
//   1) gemm128<2>: QKV projection; Q scaled by log2e/32; V stored transposed
//   2) flash_attn: no-max exp2 softmax, S^T orientation (R3/R8)
//   3) gemm128<1>: FFN1 + relu
//   4) gemm128<0>: FFN2 -> d_out (fp32)
// R8: flash_attn issue-early K/V staging + counted vmcnt + ones-MFMA rowsum
//     (97 -> 80.4 us measured; Mfma 30->41%).
// R9-R11: 256x256 deep-pipe GEMM attempts ALL regressed (109-152 us vs ~65
//     for gemm128 QKV; MfmaUtil 13-18%). Falsified: 1 block/CU kills
//     inter-block TLP, QKV grid=384 at 1 blk/CU = 1.5 dispatch rounds,
//     K=1024 = 16 K-tiles never amortizes the deep pipeline.
// R12/R13: gemm128 (256,5) REGRESSED 2.2x (176 us/dispatch): the 2nd
//     launch_bounds arg is a hard VGPR budget; allocator squeezed to 48
//     VGPR < 64-reg accumulator -> scratch spills (WRITE_SIZE 49->94 MB,
//     MfmaUtil 12%). (256,4) is structurally required for acc[4][4].
// R14: exact revert to the verified best configuration (404.36 us).
// ---------------------------------------------------------------------------

typedef __attribute__((ext_vector_type(8))) short bf16x8;
typedef __attribute__((ext_vector_type(4))) float f32x4;

__device__ __forceinline__ float bf2f(unsigned short u) {
  union { float f; uint32_t i; } v; v.i = ((uint32_t)u) << 16; return v.f;
}
__device__ __forceinline__ unsigned short f2bf(float f) {
  union { float f; uint32_t i; } v; v.f = f;
  uint32_t i = v.i;
  return (unsigned short)((i + 0x7fffu + ((i >> 16) & 1u)) >> 16);  // RNE
}

#if __has_builtin(__builtin_amdgcn_exp2f)
#define EXP2(x) __builtin_amdgcn_exp2f(x)
#else
#define EXP2(x) __expf((x) * 0.6931471805599453f)
#endif

// pack two f32 -> two bf16 (RNE) in one instr; lo gets p0
__device__ __forceinline__ uint32_t cvtpk(float p0, float p1) {
  uint32_t r;
  asm("v_cvt_pk_bf16_f32 %0, %1, %2" : "=v"(r) : "v"(p0), "v"(p1));
  return r;
}

// async 16B global->LDS (wave-uniform base + lane*16 via tid-linear chunks)
__device__ __forceinline__ void gld16(const void* g, void* l) {
  __builtin_amdgcn_global_load_lds(
      (const __attribute__((address_space(1))) uint32_t*)(uintptr_t)g,
      (__attribute__((address_space(3))) uint32_t*)(uintptr_t)l, 16, 0, 0);
}

#define SCALE_Q 0.04508422002778011f  /* log2(e) / sqrt(D=1024) */

// ---- ws layout (bf16 element offsets) -------------------------------------
#define W1B          0
#define W2B    4194304
#define B1B    8388608
#define B2B    8392704
#define BQB    8393728
#define BKB    8394752
#define BVB    8395776
#define EMBB   8396800
#define WQB   16785408
#define WKB   17833984
#define WVB   18882560
#define QOFF  19931136
#define KOFF  28319744
#define VTOFF 36708352
#define HCOFF 45096960        /* peak 53485568 elems = 102 MiB */
#define HIDOFF 8396800        /* hid overlays dead emb/Wqkv regions */

// ---- 0) fp32 -> bf16 ------------------------------------------------------
__global__ void cvt_all(const float* __restrict__ emb, const float* __restrict__ Wq,
                        const float* __restrict__ bq,  const float* __restrict__ Wk,
                        const float* __restrict__ bk,  const float* __restrict__ Wv,
                        const float* __restrict__ bv,  const float* __restrict__ W1,
                        const float* __restrict__ b1,  const float* __restrict__ W2,
                        const float* __restrict__ b2,  unsigned short* __restrict__ ws) {
  const int i4 = blockIdx.x * 256 + threadIdx.x;
  if (i4 >= 4982784) return;
  const float* s; unsigned short* d; int base;
  if      (i4 < 2097152) { s = emb; d = ws + EMBB; base = 0; }
  else if (i4 < 2359296) { s = Wq;  d = ws + WQB;  base = 2097152; }
  else if (i4 < 2621440) { s = Wk;  d = ws + WKB;  base = 2359296; }
  else if (i4 < 2883584) { s = Wv;  d = ws + WVB;  base = 2621440; }
  else if (i4 < 3932160) { s = W1;  d = ws + W1B;  base = 2883584; }
  else if (i4 < 4980736) { s = W2;  d = ws + W2B;  base = 3932160; }
  else if (i4 < 4980992) { s = bq;  d = ws + BQB;  base = 4980736; }
  else if (i4 < 4981248) { s = bk;  d = ws + BKB;  base = 4980992; }
  else if (i4 < 4981504) { s = bv;  d = ws + BVB;  base = 4981248; }
  else if (i4 < 4982528) { s = b1;  d = ws + B1B;  base = 4981504; }
  else                   { s = b2;  d = ws + B2B;  base = 4982528; }
  const int j = i4 - base;
  const float4 v = ((const float4*)s)[j];
  ushort4 o;
  o.x = f2bf(v.x); o.y = f2bf(v.y); o.z = f2bf(v.z); o.w = f2bf(v.w);
  *(ushort4*)(d + (size_t)j * 4) = o;
}

// ---- GEMM: MODE 0 = bias (fp32 out), 1 = bias+relu, 2 = QKV routing -------
// 128x128 tile, BK=64. Requires K % 64 == 0 and 64 total row-tiles.
// (256,4): hard requirement — acc[4][4] f32x4 = 64 regs; (256,5) spills (R12).
template <int MODE>
__launch_bounds__(256, 4)
__global__ void gemm128(const unsigned short* __restrict__ A,
                        const unsigned short* __restrict__ W0,
                        const unsigned short* __restrict__ W1p,
                        const unsigned short* __restrict__ W2p,
                        const unsigned short* __restrict__ bias0,
                        const unsigned short* __restrict__ bias1,
                        const unsigned short* __restrict__ bias2,
                        unsigned short* __restrict__ out0,
                        unsigned short* __restrict__ out1,
                        unsigned short* __restrict__ out2,
                        float* __restrict__ foutp,
                        int N, int K) {
  __shared__ unsigned short At[128 * 64];
  __shared__ unsigned short Bt[128 * 64];
  const int tid  = threadIdx.x;
  const int wave = tid >> 6, lane = tid & 63;
  const int quad = lane >> 4, l15 = lane & 15;

  // XCD swizzle: xcd = lid&7 owns rows ≡ xcd (mod 8), col-panels of 8.
  const int lid = blockIdx.x + blockIdx.y * gridDim.x;
  const int s_ = lid >> 3;
  const int rowBase = (((lid & 7) + ((s_ & 7) << 3)) << 7);
  const int colBase = ((s_ >> 3) << 7);

  const unsigned short* W = W0;
  const unsigned short* bias = bias0;
  int colW = colBase;
  if (MODE == 2) {
    const int which = colBase >> 10;
    if (which == 1) { W = W1p; bias = bias1; }
    if (which == 2) { W = W2p; bias = bias2; }
    colW = colBase & 1023;
  }

  // Staging: 1024 16B chunks/tile; phys chunk u = row*8 + cc holds logical
  // k-chunk ec = cc ^ (row&7). 8 consecutive lanes = one row's full 128B.
  const unsigned short* gA[4]; const unsigned short* gB[4];
  unsigned short *lA[4], *lB[4];
#pragma unroll
  for (int i = 0; i < 4; ++i) {
    const int u = tid + 256 * i;
    const int r = u >> 3, e = (((u & 7) ^ (r & 7)) * 8);
    gA[i] = A + (size_t)(rowBase + r) * K + e;
    gB[i] = W + (size_t)(colW + r) * K + e;
    lA[i] = At + u * 8;
    lB[i] = Bt + u * 8;
  }

  // Fragment offsets: row ra, logical k-chunk q8 = quad + 4*kk ->
  // addr = ra*64 + ((q8 ^ (ra&7))*8). 128B rows -> worst 2-way (free).
  const int wrow = (wave & 1) * 64, wcol = (wave >> 1) * 64;
  int aoff[2][4], boff[2][4];
#pragma unroll
  for (int kk = 0; kk < 2; ++kk)
#pragma unroll
    for (int t = 0; t < 4; ++t) {
      const int ra = wrow + t * 16 + l15;
      aoff[kk][t] = ra * 64 + (((quad + 4 * kk) ^ (ra & 7)) * 8);
      const int rb = wcol + t * 16 + l15;
      boff[kk][t] = rb * 64 + (((quad + 4 * kk) ^ (rb & 7)) * 8);
    }

  f32x4 acc[4][4] = {};
  for (int k0 = 0; k0 < K; k0 += 64) {
    __syncthreads();
#pragma unroll
    for (int i = 0; i < 4; ++i) { gld16(gA[i], lA[i]); gld16(gB[i], lB[i]); }
#pragma unroll
    for (int i = 0; i < 4; ++i) { gA[i] += 64; gB[i] += 64; }
    __syncthreads();
#pragma unroll
    for (int kk = 0; kk < 2; ++kk) {
      bf16x8 af[4], bfr[4];
#pragma unroll
      for (int t = 0; t < 4; ++t) af[t]  = *(const bf16x8*)(At + aoff[kk][t]);
#pragma unroll
      for (int t = 0; t < 4; ++t) bfr[t] = *(const bf16x8*)(Bt + boff[kk][t]);
#pragma unroll
      for (int mt = 0; mt < 4; ++mt)
#pragma unroll
        for (int nt = 0; nt < 4; ++nt)
          acc[mt][nt] = __builtin_amdgcn_mfma_f32_16x16x32_bf16(
              af[mt], bfr[nt], acc[mt][nt], 0, 0, 0);
    }
  }

#pragma unroll
  for (int mt = 0; mt < 4; ++mt) {
    const int row = rowBase + wrow + mt * 16 + quad * 4;
#pragma unroll
    for (int nt = 0; nt < 4; ++nt) {
      const int cIn = colW + wcol + nt * 16 + l15;
      const float bv = bf2f(bias[cIn]);
      if (MODE == 2) {
        const int which = colBase >> 10;
        const int h = cIn >> 6, e = cIn & 63;
#pragma unroll
        for (int r = 0; r < 4; ++r) {
          const int tok = row + r;
          const int b = tok >> 11, s = tok & 2047;
          const float v = acc[mt][nt][r] + bv;
          const size_t bh = (size_t)(b * 16 + h);
          if (which == 0)      out0[(bh * 2048 + s) * 64 + e] = f2bf(v * SCALE_Q);
          else if (which == 1) out1[(bh * 2048 + s) * 64 + e] = f2bf(v);
          else                 out2[(bh * 64 + e) * 2048 + s] = f2bf(v);  // V^T
        }
      } else if (MODE == 1) {
#pragma unroll
        for (int r = 0; r < 4; ++r) {
          const float v = fmaxf(acc[mt][nt][r] + bv, 0.0f);
          out0[(size_t)(row + r) * N + cIn] = f2bf(v);
        }
      } else {
#pragma unroll
        for (int r = 0; r < 4; ++r)
          foutp[(size_t)(row + r) * N + cIn] = acc[mt][nt][r] + bv;
      }
    }
  }
}

// ---- flash attention (R3/R8): S^T orientation, no-max exp2 softmax --------
// grid (16, 64): logical (q-block, b*16+h); XCD-swizzled.
// R8 schedule per iter (raw barriers, counted vmcnt):
//   a: issue K(it+1) -> Kt[buf^1]
//   b: QK^T from Kt[buf] + softmax + P pack (per-wave LDS)
//   c: s_waitcnt vmcnt(2) [own V(it) landed; K(it+1) stays in flight]
//      s_barrier            [all waves' V(it) landed; Kt[buf] reads done]
//   d: PV + ones-MFMA row-sum l
//   e: s_waitcnt vmcnt(0) [own K(it+1) landed]
//      s_barrier            [all waves done reading Vs + all K(it+1) landed]
//   f: issue V(it+1) -> Vs  (skipped at it=31 so kernel ends with vmcnt=0)
__launch_bounds__(256, 4)
__global__ void flash_attn(const unsigned short* __restrict__ Q,
                           const unsigned short* __restrict__ Kg,
                           const unsigned short* __restrict__ Vt,
                           unsigned short* __restrict__ Hc) {
  __shared__ unsigned short Kt[2 * 64 * 64];  // K tile dbuf [t][e], chunk-swizzled
  __shared__ unsigned short Vs[64 * 64];      // V^T tile [e][t], chunk-swizzled
  __shared__ unsigned short Pl[4][32 * 64];   // per-wave P [q][t], chunk-swizzled
  const int tid  = threadIdx.x;
  const int wave = tid >> 6, lane = tid & 63;
  const int quad = lane >> 4, l15 = lane & 15;

  // XCD swizzle: 8 bh's per XCD, q-blocks iterated within -> KV hot in L2.
  const int lid = blockIdx.x + blockIdx.y * gridDim.x;
  const int s_ = lid >> 3;
  const int bh = (lid & 7) + ((s_ & 7) << 3);
  const int q0 = ((s_ >> 3) << 7) + wave * 32;

  const size_t base = (size_t)bh * (2048 * 64);
  const unsigned short* Qb = Q  + base;
  const unsigned short* Kb = Kg + base;
  const unsigned short* Vb = Vt + base;   // [64 e][2048 t]

  // Q fragments (MFMA B operand for S^T: n=q=l15, k=e=quad*8+j)
  bf16x8 qf[2][2];
#pragma unroll
  for (int qt = 0; qt < 2; ++qt) {
    const int q = q0 + qt * 16 + l15;
#pragma unroll
    for (int kk = 0; kk < 2; ++kk)
      qf[qt][kk] = *(const bf16x8*)(Qb + (size_t)q * 64 + kk * 32 + quad * 8);
  }

  // KV staging (8-elem chunk swizzle: ec = cc ^ (row&7); 8 lanes = one 128B row)
  const int u0 = tid, u1 = tid + 256;
  const int kr0 = u0 >> 3, kc0 = (((u0 & 7) ^ (kr0 & 7)) * 8);
  const int kr1 = u1 >> 3, kc1 = (((u1 & 7) ^ (kr1 & 7)) * 8);
  const unsigned short* gK0 = Kb + (size_t)kr0 * 64 + kc0;
  const unsigned short* gK1 = Kb + (size_t)kr1 * 64 + kc1;
  const unsigned short* gV0 = Vb + (size_t)kr0 * 2048 + kc0;
  const unsigned short* gV1 = Vb + (size_t)kr1 * 2048 + kc1;
  unsigned short* lK0 = Kt + u0 * 8;
  unsigned short* lK1 = Kt + u1 * 8;
  unsigned short* lV0 = Vs + u0 * 8;
  unsigned short* lV1 = Vs + u1 * 8;

  // prologue: tile 0 into Kt[0] / Vs, full drain
  gld16(gK0, lK0); gld16(gK1, lK1);
  gld16(gV0, lV0); gld16(gV1, lV1);
  gK0 += 4096; gK1 += 4096; gV0 += 64; gV1 += 64;
  __syncthreads();

  const short oneb = (short)0x3F80;  // bf16 1.0
  const bf16x8 ones = {oneb, oneb, oneb, oneb, oneb, oneb, oneb, oneb};
  f32x4 o[2][4] = {};
  f32x4 lacc[2] = {};
  unsigned short* Pw = Pl[wave];

  for (int it = 0; it < 32; ++it) {
    const int nb = ((it + 1) & 1) * 4096;
    // (a) prefetch next K tile into the other buffer
    gld16(gK0, lK0 + nb); gld16(gK1, lK1 + nb);
    gK0 += 4096; gK1 += 4096;

    const unsigned short* Kc = Kt + (it & 1) * 4096;

    // (b) S^T = K Q^T : C row = t_local = tt*16+quad*4+r, col = q = qt*16+l15
    f32x4 st[4][2] = {};
    __builtin_amdgcn_s_setprio(1);
#pragma unroll
    for (int tt = 0; tt < 4; ++tt) {
      const int t = tt * 16 + l15;
      const bf16x8 kf0 = *(const bf16x8*)(Kc + t * 64 + ((quad       ^ (t & 7)) * 8));
      const bf16x8 kf1 = *(const bf16x8*)(Kc + t * 64 + (((quad + 4) ^ (t & 7)) * 8));
#pragma unroll
      for (int qt = 0; qt < 2; ++qt) {
        st[tt][qt] = __builtin_amdgcn_mfma_f32_16x16x32_bf16(kf0, qf[qt][0], st[tt][qt], 0, 0, 0);
        st[tt][qt] = __builtin_amdgcn_mfma_f32_16x16x32_bf16(kf1, qf[qt][1], st[tt][qt], 0, 0, 0);
      }
    }
    __builtin_amdgcn_s_setprio(0);

    // p = exp2(s) (no max: scores bounded), pack -> P[q][t] LDS (per-wave)
#pragma unroll
    for (int tt = 0; tt < 4; ++tt) {
      const int tc = tt * 2 + (quad >> 1);
#pragma unroll
      for (int qt = 0; qt < 2; ++qt) {
        const float p0 = EXP2(st[tt][qt][0]);
        const float p1 = EXP2(st[tt][qt][1]);
        const float p2 = EXP2(st[tt][qt][2]);
        const float p3 = EXP2(st[tt][qt][3]);
        uint2 w;
        w.x = cvtpk(p0, p1);
        w.y = cvtpk(p2, p3);
        const int qrow = qt * 16 + l15;
        *(uint2*)(Pw + qrow * 64 + ((tc ^ (qrow & 7)) * 8) + (quad & 1) * 4) = w;
      }
    }

    // (c) own V(it) landed (K(it+1) stays in flight), then all-waves barrier
    asm volatile("s_waitcnt vmcnt(2)" ::: "memory");
    __builtin_amdgcn_s_barrier();

    // (d) O += P V ; l += P * 1  (same-wave LDS round-trip, lgkm-ordered)
    bf16x8 pf[2][2];
#pragma unroll
    for (int mt = 0; mt < 2; ++mt) {
      const int qq = mt * 16 + l15;
      pf[mt][0] = *(const bf16x8*)(Pw + qq * 64 + ((quad       ^ (qq & 7)) * 8));
      pf[mt][1] = *(const bf16x8*)(Pw + qq * 64 + (((quad + 4) ^ (qq & 7)) * 8));
    }
    __builtin_amdgcn_s_setprio(1);
#pragma unroll
    for (int nt = 0; nt < 4; ++nt) {
      const int e = nt * 16 + l15;
      const bf16x8 vf0 = *(const bf16x8*)(Vs + e * 64 + ((quad       ^ (e & 7)) * 8));
      const bf16x8 vf1 = *(const bf16x8*)(Vs + e * 64 + (((quad + 4) ^ (e & 7)) * 8));
#pragma unroll
      for (int mt = 0; mt < 2; ++mt) {
        o[mt][nt] = __builtin_amdgcn_mfma_f32_16x16x32_bf16(pf[mt][0], vf0, o[mt][nt], 0, 0, 0);
        o[mt][nt] = __builtin_amdgcn_mfma_f32_16x16x32_bf16(pf[mt][1], vf1, o[mt][nt], 0, 0, 0);
      }
    }
    // row-sum l: D[q][*] = sum_t P[q][t]; rows match o's C-layout rows.
#pragma unroll
    for (int mt = 0; mt < 2; ++mt) {
      lacc[mt] = __builtin_amdgcn_mfma_f32_16x16x32_bf16(pf[mt][0], ones, lacc[mt], 0, 0, 0);
      lacc[mt] = __builtin_amdgcn_mfma_f32_16x16x32_bf16(pf[mt][1], ones, lacc[mt], 0, 0, 0);
    }
    __builtin_amdgcn_s_setprio(0);

    // (e) own K(it+1) landed + all waves done reading Vs
    asm volatile("s_waitcnt vmcnt(0)" ::: "memory");
    __builtin_amdgcn_s_barrier();

    // (f) prefetch next V tile (skip last so kernel ends with vmcnt=0)
    if (it < 31) {
      gld16(gV0, lV0); gld16(gV1, lV1);
      gV0 += 64; gV1 += 64;
    }
  }

  const int b = bh >> 4, h = bh & 15;
#pragma unroll
  for (int mt = 0; mt < 2; ++mt)
#pragma unroll
    for (int r = 0; r < 4; ++r) {
      const int qg = q0 + mt * 16 + quad * 4 + r;
      const float inv = __builtin_amdgcn_rcpf(lacc[mt][r]);
#pragma unroll
      for (int nt = 0; nt < 4; ++nt) {
        const int e = nt * 16 + l15;
        Hc[((size_t)b * 2048 + qg) * 1024 + h * 64 + e] = f2bf(o[mt][nt][r] * inv);
      }
    }
}

extern "C" void kernel_launch(void* const* d_in, const int* in_sizes, int n_in,
                              void* d_out, int out_size, void* d_ws, size_t ws_size,
                              hipStream_t stream) {
  const float* emb = (const float*)d_in[0];
  const float* Wq  = (const float*)d_in[1];
  const float* bq  = (const float*)d_in[2];
  const float* Wk  = (const float*)d_in[3];
  const float* bk  = (const float*)d_in[4];
  const float* Wv  = (const float*)d_in[5];
  const float* bv  = (const float*)d_in[6];
  const float* W1  = (const float*)d_in[7];
  const float* b1  = (const float*)d_in[8];
  const float* W2  = (const float*)d_in[9];
  const float* b2  = (const float*)d_in[10];

  unsigned short* ws = (unsigned short*)d_ws;
  float* out = (float*)d_out;

  cvt_all<<<19465, 256, 0, stream>>>(emb, Wq, bq, Wk, bk, Wv, bv, W1, b1, W2, b2, ws);
  gemm128<2><<<dim3(24, 64), 256, 0, stream>>>(
      ws + EMBB, ws + WQB, ws + WKB, ws + WVB, ws + BQB, ws + BKB, ws + BVB,
      ws + QOFF, ws + KOFF, ws + VTOFF, nullptr, 3072, 1024);
  flash_attn<<<dim3(16, 64), 256, 0, stream>>>(ws + QOFF, ws + KOFF, ws + VTOFF, ws + HCOFF);
  gemm128<1><<<dim3(32, 64), 256, 0, stream>>>(
      ws + HCOFF, ws + W1B, nullptr, nullptr, ws + B1B, nullptr, nullptr,
      ws + HIDOFF, nullptr, nullptr, nullptr, 4096, 1024);
  gemm128<0><<<dim3(8, 64), 256, 0, stream>>>(
      ws + HIDOFF, ws + W2B, nullptr, nullptr, ws + B2B, nullptr, nullptr,
      nullptr, nullptr, nullptr, out, 1024, 4096);
}